// Round 6
// baseline (121.225 us; speedup 1.0000x reference)
//
#include <hip/hip_runtime.h>
#include <cmath>

#define NB 2048
#define NL 375
#define NLP 384   // NL padded to 12*32
#define NEMB 32
#define DIN 480   // 15 * 32

typedef __attribute__((ext_vector_type(8))) short short8;
typedef __attribute__((ext_vector_type(4))) short short4v;
typedef __attribute__((ext_vector_type(4))) float f32x4;

__device__ inline short f2bf(float x) {
  union { float f; unsigned u; } v; v.f = x;
  unsigned r = v.u + 0x7fffu + ((v.u >> 16) & 1u);   // round-to-nearest-even
  return (short)(r >> 16);
}

// ---------------------------------------------------------------------------
// Kernel 1: sequence features — gather [B,L,32] and mean-pool over L -> x0
// Flat grid, feature varying fastest (bid%9) so each CU mixes big-table
// (miss-bound) and tiny-table (L1-hit) blocks.
// NT on ALL 4 big tables (f=0 artist_name 38MB, f=1 track_uri 128MB,
// f=2 track_name 128MB, f=4 album_name 64MB): round-5 showed nt loads keep
// FETCH_SIZE flat (within-pass reuse preserved) while raising effective
// random-line BW 1.98->2.27 TB/s (allocation-pressure/latency win).
// ---------------------------------------------------------------------------
struct SeqArgs {
  const int*   idx[9];
  const float* tab[9];
};

template <bool NT>
__device__ inline float4 gather_pool_body(const float* __restrict__ tab,
                                          const int* __restrict__ sidx,
                                          int s, int c) {
  const f32x4* tab4 = reinterpret_cast<const f32x4*>(tab);
  f32x4 acc = {0.f, 0.f, 0.f, 0.f};
  #pragma unroll
  for (int it = 0; it < 11; ++it) {
    const int l = s + it * 32;
    f32x4 v = NT ? __builtin_nontemporal_load(&tab4[(size_t)sidx[l] * 8 + c])
                 : tab4[(size_t)sidx[l] * 8 + c];
    acc += v;
  }
  {
    const int l = s + 352;
    f32x4 v = NT ? __builtin_nontemporal_load(&tab4[(size_t)sidx[l] * 8 + c])
                 : tab4[(size_t)sidx[l] * 8 + c];
    if (s < 23) acc += v;
  }
  return make_float4(acc.x, acc.y, acc.z, acc.w);
}

__global__ __launch_bounds__(256) void seq_pool_kernel(SeqArgs args, float* __restrict__ x0) {
  const int bid = blockIdx.x;
  const int f   = bid % 9;   // feature fastest among consecutive blocks
  const int b   = bid / 9;
  const int tid = threadIdx.x;

  __shared__ int sidx[NLP];
  const int*   idx = args.idx[f];
  const float* tab = args.tab[f];

  for (int i = tid; i < NLP; i += 256) sidx[i] = (i < NL) ? idx[b * NL + i] : idx[b * NL];
  __syncthreads();

  const int c = tid & 7;    // float4 column within the 32-float row
  const int s = tid >> 3;   // 0..31 slice over sequence positions

  float4 acc = (f <= 2 || f == 4) ? gather_pool_body<true>(tab, sidx, s, c)
                                  : gather_pool_body<false>(tab, sidx, s, c);

  #pragma unroll
  for (int off = 8; off <= 32; off <<= 1) {
    acc.x += __shfl_xor(acc.x, off, 64);
    acc.y += __shfl_xor(acc.y, off, 64);
    acc.z += __shfl_xor(acc.z, off, 64);
    acc.w += __shfl_xor(acc.w, off, 64);
  }

  __shared__ float4 wpart[4][8];
  const int wave = tid >> 6;
  const int lane = tid & 63;
  if (lane < 8) wpart[wave][lane] = acc;
  __syncthreads();

  if (tid < 8) {
    float4 s0 = wpart[0][tid], s1 = wpart[1][tid], s2 = wpart[2][tid], s3 = wpart[3][tid];
    const float inv = 1.0f / (float)NL;
    float4 r;
    r.x = (s0.x + s1.x + s2.x + s3.x) * inv;
    r.y = (s0.y + s1.y + s2.y + s3.y) * inv;
    r.z = (s0.z + s1.z + s2.z + s3.z) * inv;
    r.w = (s0.w + s1.w + s2.w + s3.w) * inv;
    float* out = x0 + (size_t)b * DIN + (6 + f) * NEMB + tid * 4;
    *reinterpret_cast<float4*>(out) = r;
  }
}

// ---------------------------------------------------------------------------
// Kernel 2: fused scalar-gather + DCN cross layer. One wave per row.
// ---------------------------------------------------------------------------
struct ScalArgs {
  const int*   idx[6];
  const float* tab[6];
};

__global__ __launch_bounds__(64) void cross_scalar_kernel(ScalArgs args,
                                                          float* __restrict__ x0,
                                                          const float* __restrict__ V,
                                                          const float* __restrict__ U,
                                                          const float* __restrict__ bias) {
  const int b    = blockIdx.x;
  const int lane = threadIdx.x;
  float* row = x0 + (size_t)b * DIN;

  float xv[8];
  float t[5] = {0.f, 0.f, 0.f, 0.f, 0.f};
  #pragma unroll
  for (int i = 0; i < 8; ++i) {
    int j = lane + i * 64;
    float x;
    if (i < 3) {                       // scalar-feature region: j in [0,192)
      int f = j >> 5, d = j & 31;
      x = args.tab[f][(size_t)args.idx[f][b] * NEMB + d];
    } else if (j < DIN) {              // pooled seq region from x0
      x = row[j];
    } else {
      x = 0.f;
    }
    xv[i] = x;
    if (j < DIN) {
      #pragma unroll
      for (int p = 0; p < 5; ++p) t[p] += x * V[j * 5 + p];
    }
  }
  #pragma unroll
  for (int p = 0; p < 5; ++p) {
    float v = t[p];
    for (int off = 32; off; off >>= 1) v += __shfl_xor(v, off, 64);
    t[p] = v;
  }
  #pragma unroll
  for (int i = 0; i < 8; ++i) {
    int j = lane + i * 64;
    if (j < DIN) {
      float proj = bias[j];
      #pragma unroll
      for (int p = 0; p < 5; ++p) proj += t[p] * U[p * DIN + j];
      row[j] = xv[i] * proj + xv[i];
    }
  }
}

// ---------------------------------------------------------------------------
// Kernel 3: bf16-MFMA GEMM, C = relu?(A[M,K] @ W[K,N] + bias)
// Block 64x64, 4 waves (each a 32x32 quadrant = 2x2 16x16 frags), BK=32.
// ---------------------------------------------------------------------------
template <bool RELU>
__global__ __launch_bounds__(256) void gemm_mfma_kernel(const float* __restrict__ A,
                                                        const float* __restrict__ W,
                                                        const float* __restrict__ bias,
                                                        float* __restrict__ C,
                                                        int M, int N, int K) {
  const int tid  = threadIdx.x;
  const int m0   = blockIdx.y * 64;
  const int n0   = blockIdx.x * 64;
  const int wave = tid >> 6;
  const int lane = tid & 63;
  const int wm   = wave >> 1;
  const int wn   = wave & 1;

  __shared__ short As[64][40];   // [m][k], bf16 bits
  __shared__ short Bs[64][40];   // [n][k], bf16 bits (W transposed in LDS)

  f32x4 acc[2][2];
  #pragma unroll
  for (int i = 0; i < 2; ++i)
    #pragma unroll
    for (int j = 0; j < 2; ++j)
      acc[i][j] = (f32x4){0.f, 0.f, 0.f, 0.f};

  const int am  = tid >> 2;   // 0..63
  const int akq = tid & 3;    // k chunk of 8
  const int bn  = tid & 63;   // 0..63
  const int bkg = tid >> 6;   // k chunk of 8

  for (int k0 = 0; k0 < K; k0 += 32) {
    {
      const float* ap = A + (size_t)(m0 + am) * K + k0 + akq * 8;
      float4 a0 = *reinterpret_cast<const float4*>(ap);
      float4 a1 = *reinterpret_cast<const float4*>(ap + 4);
      short8 av = { f2bf(a0.x), f2bf(a0.y), f2bf(a0.z), f2bf(a0.w),
                    f2bf(a1.x), f2bf(a1.y), f2bf(a1.z), f2bf(a1.w) };
      *reinterpret_cast<short8*>(&As[am][akq * 8]) = av;
    }
    {
      float bv[8];
      #pragma unroll
      for (int i = 0; i < 8; ++i)
        bv[i] = W[(size_t)(k0 + bkg * 8 + i) * N + n0 + bn];
      short8 wv = { f2bf(bv[0]), f2bf(bv[1]), f2bf(bv[2]), f2bf(bv[3]),
                    f2bf(bv[4]), f2bf(bv[5]), f2bf(bv[6]), f2bf(bv[7]) };
      *reinterpret_cast<short8*>(&Bs[bn][bkg * 8]) = wv;
    }
    __syncthreads();

    short8 bf[2];
    #pragma unroll
    for (int fn = 0; fn < 2; ++fn)
      bf[fn] = *reinterpret_cast<const short8*>(&Bs[wn * 32 + fn * 16 + (lane & 15)][(lane >> 4) * 8]);
    #pragma unroll
    for (int fm = 0; fm < 2; ++fm) {
      short8 af = *reinterpret_cast<const short8*>(&As[wm * 32 + fm * 16 + (lane & 15)][(lane >> 4) * 8]);
      #pragma unroll
      for (int fn = 0; fn < 2; ++fn)
        acc[fm][fn] = __builtin_amdgcn_mfma_f32_16x16x32_bf16(af, bf[fn], acc[fm][fn], 0, 0, 0);
    }
    __syncthreads();
  }

  #pragma unroll
  for (int fm = 0; fm < 2; ++fm) {
    #pragma unroll
    for (int fn = 0; fn < 2; ++fn) {
      const int col  = n0 + wn * 32 + fn * 16 + (lane & 15);
      const float bc = bias[col];
      #pragma unroll
      for (int r = 0; r < 4; ++r) {
        const int m = m0 + wm * 32 + fm * 16 + (lane >> 4) * 4 + r;
        float x = acc[fm][fn][r] + bc;
        if (RELU) x = fmaxf(x, 0.f);
        C[(size_t)m * N + col] = x;
      }
    }
  }
}

// ---------------------------------------------------------------------------
// Kernel 4: layer-3 bf16-MFMA GEMM (N=128) + bias + row L2-normalize -> out
// ---------------------------------------------------------------------------
__global__ __launch_bounds__(256) void gemm3_norm_kernel(const float* __restrict__ A,
                                                         const float* __restrict__ W,
                                                         const float* __restrict__ bias,
                                                         float* __restrict__ out,
                                                         int M, int K) {
  const int N    = 128;
  const int tid  = threadIdx.x;
  const int m0   = blockIdx.x * 32;
  const int wave = tid >> 6;
  const int lane = tid & 63;

  __shared__ short As[32][40];    // [m][k]
  __shared__ short Bs[128][40];   // [n][k]

  f32x4 acc[2][2];
  #pragma unroll
  for (int i = 0; i < 2; ++i)
    #pragma unroll
    for (int j = 0; j < 2; ++j)
      acc[i][j] = (f32x4){0.f, 0.f, 0.f, 0.f};

  const int am  = tid >> 3;   // 0..31
  const int akq = tid & 7;    // k chunk of 4
  const int bn  = tid & 127;  // 0..127
  const int bkg = tid >> 7;   // k chunk of 16

  for (int k0 = 0; k0 < K; k0 += 32) {
    {
      float4 a0 = *reinterpret_cast<const float4*>(A + (size_t)(m0 + am) * K + k0 + akq * 4);
      short4v av = { f2bf(a0.x), f2bf(a0.y), f2bf(a0.z), f2bf(a0.w) };
      *reinterpret_cast<short4v*>(&As[am][akq * 4]) = av;
    }
    {
      float bv[16];
      #pragma unroll
      for (int i = 0; i < 16; ++i)
        bv[i] = W[(size_t)(k0 + bkg * 16 + i) * N + bn];
      short8 w0 = { f2bf(bv[0]),  f2bf(bv[1]),  f2bf(bv[2]),  f2bf(bv[3]),
                    f2bf(bv[4]),  f2bf(bv[5]),  f2bf(bv[6]),  f2bf(bv[7]) };
      short8 w1 = { f2bf(bv[8]),  f2bf(bv[9]),  f2bf(bv[10]), f2bf(bv[11]),
                    f2bf(bv[12]), f2bf(bv[13]), f2bf(bv[14]), f2bf(bv[15]) };
      *reinterpret_cast<short8*>(&Bs[bn][bkg * 16])     = w0;
      *reinterpret_cast<short8*>(&Bs[bn][bkg * 16 + 8]) = w1;
    }
    __syncthreads();

    short8 bf[2];
    #pragma unroll
    for (int fn = 0; fn < 2; ++fn)
      bf[fn] = *reinterpret_cast<const short8*>(&Bs[wave * 32 + fn * 16 + (lane & 15)][(lane >> 4) * 8]);
    #pragma unroll
    for (int fm = 0; fm < 2; ++fm) {
      short8 af = *reinterpret_cast<const short8*>(&As[fm * 16 + (lane & 15)][(lane >> 4) * 8]);
      #pragma unroll
      for (int fn = 0; fn < 2; ++fn)
        acc[fm][fn] = __builtin_amdgcn_mfma_f32_16x16x32_bf16(af, bf[fn], acc[fm][fn], 0, 0, 0);
    }
    __syncthreads();
  }

  float val[2][2][4];
  float psq[2][4] = {};
  #pragma unroll
  for (int fm = 0; fm < 2; ++fm)
    #pragma unroll
    for (int fn = 0; fn < 2; ++fn) {
      const int col  = wave * 32 + fn * 16 + (lane & 15);
      const float bc = bias[col];
      #pragma unroll
      for (int r = 0; r < 4; ++r) {
        float x = acc[fm][fn][r] + bc;
        val[fm][fn][r] = x;
        psq[fm][r] += x * x;
      }
    }

  #pragma unroll
  for (int off = 1; off < 16; off <<= 1)
    #pragma unroll
    for (int fm = 0; fm < 2; ++fm)
      #pragma unroll
      for (int r = 0; r < 4; ++r)
        psq[fm][r] += __shfl_xor(psq[fm][r], off, 64);

  __shared__ float part[4][32];
  if ((lane & 15) == 0) {
    #pragma unroll
    for (int fm = 0; fm < 2; ++fm)
      #pragma unroll
      for (int r = 0; r < 4; ++r)
        part[wave][fm * 16 + (lane >> 4) * 4 + r] = psq[fm][r];
  }
  __syncthreads();

  __shared__ float rn[32];
  if (tid < 32)
    rn[tid] = 1.0f / sqrtf(fmaxf(part[0][tid] + part[1][tid] + part[2][tid] + part[3][tid], 1e-12f));
  __syncthreads();

  #pragma unroll
  for (int fm = 0; fm < 2; ++fm)
    #pragma unroll
    for (int fn = 0; fn < 2; ++fn) {
      const int col = wave * 32 + fn * 16 + (lane & 15);
      #pragma unroll
      for (int r = 0; r < 4; ++r) {
        const int mrow = fm * 16 + (lane >> 4) * 4 + r;
        out[(size_t)(m0 + mrow) * N + col] = val[fm][fn][r] * rn[mrow];
      }
    }
}

// ---------------------------------------------------------------------------
// kernel_launch
// ---------------------------------------------------------------------------
extern "C" void kernel_launch(void* const* d_in, const int* in_sizes, int n_in,
                              void* d_out, int out_size, void* d_ws, size_t ws_size,
                              hipStream_t stream) {
  const int*   idx[15];
  const float* tab[15];
  for (int i = 0; i < 15; ++i) {
    idx[i] = (const int*)d_in[i];
    tab[i] = (const float*)d_in[15 + i];
  }
  const float* cross_V = (const float*)d_in[30];
  const float* cross_U = (const float*)d_in[31];
  const float* cross_b = (const float*)d_in[32];
  const float* W1 = (const float*)d_in[33];
  const float* b1 = (const float*)d_in[34];
  const float* W2 = (const float*)d_in[35];
  const float* b2 = (const float*)d_in[36];
  const float* W3 = (const float*)d_in[37];
  const float* b3 = (const float*)d_in[38];
  float* out = (float*)d_out;

  // workspace: x0 [B,480] | h1 [B,512] | h2 [B,256]  (~10.2 MB)
  float* x0 = (float*)d_ws;
  float* h1 = x0 + (size_t)NB * DIN;
  float* h2 = h1 + (size_t)NB * 512;

  SeqArgs sa;
  for (int i = 0; i < 9; ++i) { sa.idx[i] = idx[6 + i]; sa.tab[i] = tab[6 + i]; }
  ScalArgs ca;
  for (int i = 0; i < 6; ++i) { ca.idx[i] = idx[i]; ca.tab[i] = tab[i]; }

  hipLaunchKernelGGL(seq_pool_kernel, dim3(NB * 9), dim3(256), 0, stream, sa, x0);
  hipLaunchKernelGGL(cross_scalar_kernel, dim3(NB), dim3(64), 0, stream,
                     ca, x0, cross_V, cross_U, cross_b);
  hipLaunchKernelGGL((gemm_mfma_kernel<true>), dim3(512 / 64, NB / 64), dim3(256), 0, stream,
                     x0, W1, b1, h1, NB, 512, DIN);
  hipLaunchKernelGGL((gemm_mfma_kernel<true>), dim3(256 / 64, NB / 64), dim3(256), 0, stream,
                     h1, W2, b2, h2, NB, 256, 512);
  hipLaunchKernelGGL(gemm3_norm_kernel, dim3(NB / 32), dim3(256), 0, stream,
                     h2, W3, b3, out, NB, 256);
}

// Round 7
// 110.179 us; speedup vs baseline: 1.1003x; 1.1003x over previous
//
#include <hip/hip_runtime.h>
#include <cmath>

#define NB 2048
#define NL 375
#define NLP 384   // NL padded to 12*32
#define NEMB 32
#define DIN 480   // 15 * 32

typedef __attribute__((ext_vector_type(8))) short short8;
typedef __attribute__((ext_vector_type(4))) short short4v;
typedef __attribute__((ext_vector_type(4))) float f32x4;

__device__ inline short f2bf(float x) {
  union { float f; unsigned u; } v; v.f = x;
  unsigned r = v.u + 0x7fffu + ((v.u >> 16) & 1u);   // round-to-nearest-even
  return (short)(r >> 16);
}

// ---------------------------------------------------------------------------
// Kernel 1: sequence features — gather [B,L,32] and mean-pool over L -> x0
// Flat grid, feature varying fastest (bid%9). NT ONLY on f=1,2 (the two
// 1M-row, ~1.4x-reuse tables): round-5 showed +15% from nt there; round-6
// showed nt on the higher-reuse tables (f=0 2.6x, f=4 1.5x) REGRESSES
// (repeat-hits pushed out of fast cache path) -> reverted.
// ---------------------------------------------------------------------------
struct SeqArgs {
  const int*   idx[9];
  const float* tab[9];
};

template <bool NT>
__device__ inline float4 gather_pool_body(const float* __restrict__ tab,
                                          const int* __restrict__ sidx,
                                          int s, int c) {
  const f32x4* tab4 = reinterpret_cast<const f32x4*>(tab);
  f32x4 acc = {0.f, 0.f, 0.f, 0.f};
  #pragma unroll
  for (int it = 0; it < 11; ++it) {
    const int l = s + it * 32;
    f32x4 v = NT ? __builtin_nontemporal_load(&tab4[(size_t)sidx[l] * 8 + c])
                 : tab4[(size_t)sidx[l] * 8 + c];
    acc += v;
  }
  {
    const int l = s + 352;
    f32x4 v = NT ? __builtin_nontemporal_load(&tab4[(size_t)sidx[l] * 8 + c])
                 : tab4[(size_t)sidx[l] * 8 + c];
    if (s < 23) acc += v;
  }
  return make_float4(acc.x, acc.y, acc.z, acc.w);
}

__global__ __launch_bounds__(256) void seq_pool_kernel(SeqArgs args, float* __restrict__ x0) {
  const int bid = blockIdx.x;
  const int f   = bid % 9;   // feature fastest among consecutive blocks
  const int b   = bid / 9;
  const int tid = threadIdx.x;

  __shared__ int sidx[NLP];
  const int*   idx = args.idx[f];
  const float* tab = args.tab[f];

  // index stream is single-touch per pass -> nt to avoid polluting caches
  for (int i = tid; i < NLP; i += 256)
    sidx[i] = (i < NL) ? __builtin_nontemporal_load(&idx[b * NL + i])
                       : __builtin_nontemporal_load(&idx[b * NL]);
  __syncthreads();

  const int c = tid & 7;    // float4 column within the 32-float row
  const int s = tid >> 3;   // 0..31 slice over sequence positions

  float4 acc = (f == 1 || f == 2) ? gather_pool_body<true>(tab, sidx, s, c)
                                  : gather_pool_body<false>(tab, sidx, s, c);

  #pragma unroll
  for (int off = 8; off <= 32; off <<= 1) {
    acc.x += __shfl_xor(acc.x, off, 64);
    acc.y += __shfl_xor(acc.y, off, 64);
    acc.z += __shfl_xor(acc.z, off, 64);
    acc.w += __shfl_xor(acc.w, off, 64);
  }

  __shared__ float4 wpart[4][8];
  const int wave = tid >> 6;
  const int lane = tid & 63;
  if (lane < 8) wpart[wave][lane] = acc;
  __syncthreads();

  if (tid < 8) {
    float4 s0 = wpart[0][tid], s1 = wpart[1][tid], s2 = wpart[2][tid], s3 = wpart[3][tid];
    const float inv = 1.0f / (float)NL;
    float4 r;
    r.x = (s0.x + s1.x + s2.x + s3.x) * inv;
    r.y = (s0.y + s1.y + s2.y + s3.y) * inv;
    r.z = (s0.z + s1.z + s2.z + s3.z) * inv;
    r.w = (s0.w + s1.w + s2.w + s3.w) * inv;
    float* out = x0 + (size_t)b * DIN + (6 + f) * NEMB + tid * 4;
    *reinterpret_cast<float4*>(out) = r;
  }
}

// ---------------------------------------------------------------------------
// Kernel 2: fused scalar-gather + DCN cross layer. One wave per row.
// Reads seq region from x0 (fp32), writes the WHOLE crossed row as BF16 to
// x0b — numerically identical to the old fp32-write + staging-convert path.
// ---------------------------------------------------------------------------
struct ScalArgs {
  const int*   idx[6];
  const float* tab[6];
};

__global__ __launch_bounds__(64) void cross_scalar_kernel(ScalArgs args,
                                                          const float* __restrict__ x0,
                                                          short* __restrict__ x0b,
                                                          const float* __restrict__ V,
                                                          const float* __restrict__ U,
                                                          const float* __restrict__ bias) {
  const int b    = blockIdx.x;
  const int lane = threadIdx.x;
  const float* row = x0 + (size_t)b * DIN;
  short* rowb = x0b + (size_t)b * DIN;

  float xv[8];
  float t[5] = {0.f, 0.f, 0.f, 0.f, 0.f};
  #pragma unroll
  for (int i = 0; i < 8; ++i) {
    int j = lane + i * 64;
    float x;
    if (i < 3) {                       // scalar-feature region: j in [0,192)
      int f = j >> 5, d = j & 31;
      x = args.tab[f][(size_t)args.idx[f][b] * NEMB + d];
    } else if (j < DIN) {              // pooled seq region from x0
      x = row[j];
    } else {
      x = 0.f;
    }
    xv[i] = x;
    if (j < DIN) {
      #pragma unroll
      for (int p = 0; p < 5; ++p) t[p] += x * V[j * 5 + p];
    }
  }
  #pragma unroll
  for (int p = 0; p < 5; ++p) {
    float v = t[p];
    for (int off = 32; off; off >>= 1) v += __shfl_xor(v, off, 64);
    t[p] = v;
  }
  #pragma unroll
  for (int i = 0; i < 8; ++i) {
    int j = lane + i * 64;
    if (j < DIN) {
      float proj = bias[j];
      #pragma unroll
      for (int p = 0; p < 5; ++p) proj += t[p] * U[p * DIN + j];
      rowb[j] = f2bf(xv[i] * proj + xv[i]);
    }
  }
}

// ---------------------------------------------------------------------------
// Kernel 3: bf16-MFMA GEMM, Cb = bf16(relu(Ab[M,K] @ W[K,N] + bias))
// A is bf16 (K-major), C written as bf16. Block 64x64, 4 waves, BK=32.
// ---------------------------------------------------------------------------
template <bool RELU>
__global__ __launch_bounds__(256) void gemm_mfma_kernel(const short* __restrict__ A,
                                                        const float* __restrict__ W,
                                                        const float* __restrict__ bias,
                                                        short* __restrict__ C,
                                                        int M, int N, int K) {
  const int tid  = threadIdx.x;
  const int m0   = blockIdx.y * 64;
  const int n0   = blockIdx.x * 64;
  const int wave = tid >> 6;
  const int lane = tid & 63;
  const int wm   = wave >> 1;
  const int wn   = wave & 1;

  __shared__ short As[64][40];   // [m][k], bf16 bits
  __shared__ short Bs[64][40];   // [n][k], bf16 bits (W transposed in LDS)

  f32x4 acc[2][2];
  #pragma unroll
  for (int i = 0; i < 2; ++i)
    #pragma unroll
    for (int j = 0; j < 2; ++j)
      acc[i][j] = (f32x4){0.f, 0.f, 0.f, 0.f};

  const int am  = tid >> 2;   // 0..63
  const int akq = tid & 3;    // k chunk of 8
  const int bn  = tid & 63;   // 0..63
  const int bkg = tid >> 6;   // k chunk of 8

  for (int k0 = 0; k0 < K; k0 += 32) {
    {
      // A already bf16: one 16B copy per thread
      short8 av = *reinterpret_cast<const short8*>(&A[(size_t)(m0 + am) * K + k0 + akq * 8]);
      *reinterpret_cast<short8*>(&As[am][akq * 8]) = av;
    }
    {
      float bv[8];
      #pragma unroll
      for (int i = 0; i < 8; ++i)
        bv[i] = W[(size_t)(k0 + bkg * 8 + i) * N + n0 + bn];
      short8 wv = { f2bf(bv[0]), f2bf(bv[1]), f2bf(bv[2]), f2bf(bv[3]),
                    f2bf(bv[4]), f2bf(bv[5]), f2bf(bv[6]), f2bf(bv[7]) };
      *reinterpret_cast<short8*>(&Bs[bn][bkg * 8]) = wv;
    }
    __syncthreads();

    short8 bf[2];
    #pragma unroll
    for (int fn = 0; fn < 2; ++fn)
      bf[fn] = *reinterpret_cast<const short8*>(&Bs[wn * 32 + fn * 16 + (lane & 15)][(lane >> 4) * 8]);
    #pragma unroll
    for (int fm = 0; fm < 2; ++fm) {
      short8 af = *reinterpret_cast<const short8*>(&As[wm * 32 + fm * 16 + (lane & 15)][(lane >> 4) * 8]);
      #pragma unroll
      for (int fn = 0; fn < 2; ++fn)
        acc[fm][fn] = __builtin_amdgcn_mfma_f32_16x16x32_bf16(af, bf[fn], acc[fm][fn], 0, 0, 0);
    }
    __syncthreads();
  }

  #pragma unroll
  for (int fm = 0; fm < 2; ++fm) {
    #pragma unroll
    for (int fn = 0; fn < 2; ++fn) {
      const int col  = n0 + wn * 32 + fn * 16 + (lane & 15);
      const float bc = bias[col];
      #pragma unroll
      for (int r = 0; r < 4; ++r) {
        const int m = m0 + wm * 32 + fm * 16 + (lane >> 4) * 4 + r;
        float x = acc[fm][fn][r] + bc;
        if (RELU) x = fmaxf(x, 0.f);
        C[(size_t)m * N + col] = f2bf(x);
      }
    }
  }
}

// ---------------------------------------------------------------------------
// Kernel 4: layer-3 bf16-MFMA GEMM (N=128) + bias + row L2-normalize -> out
// A = h2b bf16; out fp32 (d_out).
// ---------------------------------------------------------------------------
__global__ __launch_bounds__(256) void gemm3_norm_kernel(const short* __restrict__ A,
                                                         const float* __restrict__ W,
                                                         const float* __restrict__ bias,
                                                         float* __restrict__ out,
                                                         int M, int K) {
  const int N    = 128;
  const int tid  = threadIdx.x;
  const int m0   = blockIdx.x * 32;
  const int wave = tid >> 6;
  const int lane = tid & 63;

  __shared__ short As[32][40];    // [m][k]
  __shared__ short Bs[128][40];   // [n][k]

  f32x4 acc[2][2];
  #pragma unroll
  for (int i = 0; i < 2; ++i)
    #pragma unroll
    for (int j = 0; j < 2; ++j)
      acc[i][j] = (f32x4){0.f, 0.f, 0.f, 0.f};

  const int am  = tid >> 3;   // 0..31
  const int akq = tid & 7;    // k chunk of 4
  const int bn  = tid & 127;  // 0..127
  const int bkg = tid >> 7;   // k chunk of 16

  for (int k0 = 0; k0 < K; k0 += 32) {
    {
      short4v av = *reinterpret_cast<const short4v*>(&A[(size_t)(m0 + am) * K + k0 + akq * 4]);
      *reinterpret_cast<short4v*>(&As[am][akq * 4]) = av;
    }
    {
      float bv[16];
      #pragma unroll
      for (int i = 0; i < 16; ++i)
        bv[i] = W[(size_t)(k0 + bkg * 16 + i) * N + bn];
      short8 w0 = { f2bf(bv[0]),  f2bf(bv[1]),  f2bf(bv[2]),  f2bf(bv[3]),
                    f2bf(bv[4]),  f2bf(bv[5]),  f2bf(bv[6]),  f2bf(bv[7]) };
      short8 w1 = { f2bf(bv[8]),  f2bf(bv[9]),  f2bf(bv[10]), f2bf(bv[11]),
                    f2bf(bv[12]), f2bf(bv[13]), f2bf(bv[14]), f2bf(bv[15]) };
      *reinterpret_cast<short8*>(&Bs[bn][bkg * 16])     = w0;
      *reinterpret_cast<short8*>(&Bs[bn][bkg * 16 + 8]) = w1;
    }
    __syncthreads();

    short8 bf[2];
    #pragma unroll
    for (int fn = 0; fn < 2; ++fn)
      bf[fn] = *reinterpret_cast<const short8*>(&Bs[wave * 32 + fn * 16 + (lane & 15)][(lane >> 4) * 8]);
    #pragma unroll
    for (int fm = 0; fm < 2; ++fm) {
      short8 af = *reinterpret_cast<const short8*>(&As[fm * 16 + (lane & 15)][(lane >> 4) * 8]);
      #pragma unroll
      for (int fn = 0; fn < 2; ++fn)
        acc[fm][fn] = __builtin_amdgcn_mfma_f32_16x16x32_bf16(af, bf[fn], acc[fm][fn], 0, 0, 0);
    }
    __syncthreads();
  }

  float val[2][2][4];
  float psq[2][4] = {};
  #pragma unroll
  for (int fm = 0; fm < 2; ++fm)
    #pragma unroll
    for (int fn = 0; fn < 2; ++fn) {
      const int col  = wave * 32 + fn * 16 + (lane & 15);
      const float bc = bias[col];
      #pragma unroll
      for (int r = 0; r < 4; ++r) {
        float x = acc[fm][fn][r] + bc;
        val[fm][fn][r] = x;
        psq[fm][r] += x * x;
      }
    }

  #pragma unroll
  for (int off = 1; off < 16; off <<= 1)
    #pragma unroll
    for (int fm = 0; fm < 2; ++fm)
      #pragma unroll
      for (int r = 0; r < 4; ++r)
        psq[fm][r] += __shfl_xor(psq[fm][r], off, 64);

  __shared__ float part[4][32];
  if ((lane & 15) == 0) {
    #pragma unroll
    for (int fm = 0; fm < 2; ++fm)
      #pragma unroll
      for (int r = 0; r < 4; ++r)
        part[wave][fm * 16 + (lane >> 4) * 4 + r] = psq[fm][r];
  }
  __syncthreads();

  __shared__ float rn[32];
  if (tid < 32)
    rn[tid] = 1.0f / sqrtf(fmaxf(part[0][tid] + part[1][tid] + part[2][tid] + part[3][tid], 1e-12f));
  __syncthreads();

  #pragma unroll
  for (int fm = 0; fm < 2; ++fm)
    #pragma unroll
    for (int fn = 0; fn < 2; ++fn) {
      const int col = wave * 32 + fn * 16 + (lane & 15);
      #pragma unroll
      for (int r = 0; r < 4; ++r) {
        const int mrow = fm * 16 + (lane >> 4) * 4 + r;
        out[(size_t)(m0 + mrow) * N + col] = val[fm][fn][r] * rn[mrow];
      }
    }
}

// ---------------------------------------------------------------------------
// kernel_launch
// ---------------------------------------------------------------------------
extern "C" void kernel_launch(void* const* d_in, const int* in_sizes, int n_in,
                              void* d_out, int out_size, void* d_ws, size_t ws_size,
                              hipStream_t stream) {
  const int*   idx[15];
  const float* tab[15];
  for (int i = 0; i < 15; ++i) {
    idx[i] = (const int*)d_in[i];
    tab[i] = (const float*)d_in[15 + i];
  }
  const float* cross_V = (const float*)d_in[30];
  const float* cross_U = (const float*)d_in[31];
  const float* cross_b = (const float*)d_in[32];
  const float* W1 = (const float*)d_in[33];
  const float* b1 = (const float*)d_in[34];
  const float* W2 = (const float*)d_in[35];
  const float* b2 = (const float*)d_in[36];
  const float* W3 = (const float*)d_in[37];
  const float* b3 = (const float*)d_in[38];
  float* out = (float*)d_out;

  // workspace: x0 fp32 [B,480] | x0b bf16 [B,480] | h1b bf16 [B,512] | h2b bf16 [B,256]
  float* x0  = (float*)d_ws;
  short* x0b = (short*)(x0 + (size_t)NB * DIN);
  short* h1b = x0b + (size_t)NB * DIN;
  short* h2b = h1b + (size_t)NB * 512;

  SeqArgs sa;
  for (int i = 0; i < 9; ++i) { sa.idx[i] = idx[6 + i]; sa.tab[i] = tab[6 + i]; }
  ScalArgs ca;
  for (int i = 0; i < 6; ++i) { ca.idx[i] = idx[i]; ca.tab[i] = tab[i]; }

  hipLaunchKernelGGL(seq_pool_kernel, dim3(NB * 9), dim3(256), 0, stream, sa, x0);
  hipLaunchKernelGGL(cross_scalar_kernel, dim3(NB), dim3(64), 0, stream,
                     ca, x0, x0b, cross_V, cross_U, cross_b);
  hipLaunchKernelGGL((gemm_mfma_kernel<true>), dim3(512 / 64, NB / 64), dim3(256), 0, stream,
                     x0b, W1, b1, h1b, NB, 512, DIN);
  hipLaunchKernelGGL((gemm_mfma_kernel<true>), dim3(256 / 64, NB / 64), dim3(256), 0, stream,
                     h1b, W2, b2, h2b, NB, 256, 512);
  hipLaunchKernelGGL(gemm3_norm_kernel, dim3(NB / 32), dim3(256), 0, stream,
                     h2b, W3, b3, out, NB, 256);
}